// Round 11
// baseline (282.944 us; speedup 1.0000x reference)
//
#include <hip/hip_runtime.h>

#define D 128

typedef __attribute__((ext_vector_type(8))) short short8;
typedef __attribute__((ext_vector_type(4))) float f32x4;

// fp32 -> bf16 bits, round-to-nearest-even
__device__ inline unsigned int f2bf_bits(float f) {
    unsigned int u = __float_as_uint(f);
    return (u + 0x7FFFu + ((u >> 16) & 1u)) >> 16;
}

// ---------------- fused prep: x cast+pack | weight pack | coarse hist | zero-row ----
// block roles: [0,6250) x-pack, [6250,6506) wsplit, [6506,6570) coarse hist
// (64 blocks, per-block partials -> no pre-zero), 6570 zero feature row N.
__global__ __launch_bounds__(256) void prep_kernel(
    const float* __restrict__ x,
    const float* __restrict__ W1l, const float* __restrict__ W1r,
    const float* __restrict__ W2l, const float* __restrict__ W2r,
    const int* __restrict__ dst,
    unsigned short* __restrict__ fbf,
    float* __restrict__ xpk,
    unsigned short* __restrict__ w1_hi, unsigned short* __restrict__ w1_lo,
    unsigned short* __restrict__ w2_hi, unsigned short* __restrict__ w2_lo,
    int* __restrict__ part, int N, int E)
{
    const int t = threadIdx.x;
    const int b = blockIdx.x;
    if (b < 6250) {
        // x: row-major bf16 (gather) + packed A-frag fp32 (gemm self term)
        const int i = b * 256 + t;                 // 0..1599999
        const int hw = i >> 5, l5 = i & 31;
        f32x4 v = *(const f32x4*)(x + (size_t)hw * D + l5 * 4);
        ushort4 hv;
        hv.x = (unsigned short)f2bf_bits(v.x);
        hv.y = (unsigned short)f2bf_bits(v.y);
        hv.z = (unsigned short)f2bf_bits(v.z);
        hv.w = (unsigned short)f2bf_bits(v.w);
        *(ushort4*)(fbf + (size_t)hw * D + l5 * 4) = hv;
        const int tile = hw >> 4, r16 = hw & 15;
        const int ks = l5 >> 3, q = (l5 & 7) >> 1, jb = (l5 & 1) * 4;
        const size_t p = ((size_t)(tile * 4 + ks) * 64 + q * 16 + r16) * 8 + jb;
        *(f32x4*)(xpk + p) = v;
    } else if (b < 6506) {
        // weight pack: B-frag order + bf16 hi/lo split, both layers
        int gidx = (b - 6250) * 256 + t;           // 0..65535
        int sel = gidx >> 15;
        int idx = gidx & 32767;
        int tt = idx >> 12;
        int ks = (idx >> 9) & 7;
        int lane = (idx >> 3) & 63;
        int j = idx & 7;
        int q = lane >> 4, r16 = lane & 15;
        int k = ks * 32 + q * 8 + j;
        int c = tt * 16 + r16;
        const float* Wl = sel ? W2l : W1l;
        const float* Wr = sel ? W2r : W1r;
        float v = (k < 128) ? Wl[k * 128 + c] : Wr[(k - 128) * 128 + c];
        unsigned int h = f2bf_bits(v);
        float hf = __uint_as_float(h << 16);
        unsigned int l = f2bf_bits(v - hf);
        (sel ? w2_hi : w1_hi)[idx] = (unsigned short)h;
        (sel ? w2_lo : w1_lo)[idx] = (unsigned short)l;
    } else if (b < 6570) {
        __shared__ int h[256];
        h[t] = 0;
        __syncthreads();
        const int b3 = b - 6506;
        for (int e = b3 * 256 + t; e < E; e += 64 * 256)
            atomicAdd(&h[dst[e] >> 8], 1);
        __syncthreads();
        part[b3 * 256 + t] = h[t];
    } else {
        // zero sentinel row N of the bf16 feature table (pad target)
        if (t < 64) ((int*)(fbf + (size_t)N * D))[t] = 0;
    }
}

// ---------------- scan 256 bucket counts (sum of 64 per-block partials) ----------------
__global__ __launch_bounds__(256) void scan256_kernel(const int* __restrict__ part,
                                                      int* __restrict__ cbase,
                                                      int* __restrict__ gcur) {
    __shared__ int wsum[4];
    const int t = threadIdx.x, lane = t & 63, wv = t >> 6;
    int v = 0;
    for (int b = 0; b < 64; ++b) v += part[b * 256 + t];
    int s = v;
#pragma unroll
    for (int o = 1; o < 64; o <<= 1) {
        int u = __shfl_up(s, o, 64);
        if (lane >= o) s += u;
    }
    if (lane == 63) wsum[wv] = s;
    __syncthreads();
    int add = 0;
    for (int w = 0; w < wv; ++w) add += wsum[w];
    cbase[t + 1] = s + add;
    if (t == 0) cbase[0] = 0;
    gcur[t] = s + add - v;
}

// ---------------- coarse multisplit scatter ----------------
// Entry = (b<<24) | (src<<8) | (dst&255)   [src < 65536, b < 256]
#define CCHUNK 4096
__global__ __launch_bounds__(256) void coarse_scatter_kernel(
    const int* __restrict__ src, const int* __restrict__ dst,
    int* __restrict__ gcur, unsigned int* __restrict__ centries, int E)
{
    __shared__ int h[256];
    __shared__ int base[256];
    __shared__ unsigned int stage[CCHUNK];
    const int t = threadIdx.x;
    const int e0 = blockIdx.x * CCHUNK;
    h[t] = 0;
    __syncthreads();
#pragma unroll
    for (int i = 0; i < 16; ++i) {
        int e = e0 + i * 256 + t;
        unsigned int u = 0xFFFFFFFFu;
        if (e < E) {
            int d = dst[e];
            int s = src[e];
            int b = d >> 8;
            u = ((unsigned)b << 24) | ((unsigned)s << 8) | (unsigned)(d & 255);
            atomicAdd(&h[b], 1);
        }
        stage[i * 256 + t] = u;
    }
    __syncthreads();
    base[t] = atomicAdd(&gcur[t], h[t]);
    __syncthreads();
    h[t] = 0;
    __syncthreads();
#pragma unroll
    for (int i = 0; i < 16; ++i) {
        unsigned int u = stage[i * 256 + t];
        if (u != 0xFFFFFFFFu) {
            int b = u >> 24;
            int r = atomicAdd(&h[b], 1);
            int pos = base[b] + r;
            if (pos < E) centries[pos] = u & 0x00FFFFFFu;  // clamp guards rocprof replays
        }
    }
}

// ---------------- fine bucket: per-node padded u16 CSR + off/deg, LDS-staged ----------------
// Node segments padded to x16 with sentinel src = N (zero row). Bucket b's
// padded region starts at align16(cbase[b]) + b*SLACK (SLACK covers worst-case
// pad growth + alignment), so offsets are globally exact without a re-scan.
#define DCAP 8192
#define SLACK 3856
__global__ __launch_bounds__(256) void fine_bucket_kernel(
    const unsigned int* __restrict__ centries,
    const int* __restrict__ cbase,
    int* __restrict__ offo, unsigned short* __restrict__ deg16,
    unsigned short* __restrict__ csr16, int N, int E)
{
    __shared__ int h[256], ex[256], wsum[4];
    __shared__ int tot_sh;
    __shared__ __align__(16) unsigned short stg[DCAP];
    const int t = threadIdx.x, lane = t & 63, wv = t >> 6;
    const int b = blockIdx.x;
    const int s0 = cbase[b];
    const int cnt = cbase[b + 1] - s0;
    const int base = ((s0 + 15) & ~15) + b * SLACK;
    h[t] = 0;
    __syncthreads();
    for (int i = t; i < cnt; i += 256)
        atomicAdd(&h[centries[s0 + i] & 255], 1);
    __syncthreads();
    const int v = h[t];
    const int pdv = (v + 15) & ~15;          // padded degree
    int s = pdv;
#pragma unroll
    for (int o = 1; o < 64; o <<= 1) {
        int u = __shfl_up(s, o, 64);
        if (lane >= o) s += u;
    }
    if (lane == 63) wsum[wv] = s;
    __syncthreads();
    int add = 0;
    for (int w = 0; w < wv; ++w) add += wsum[w];
    const int exc = s + add - pdv;
    ex[t] = exc;
    if (t == 255) tot_sh = exc + pdv;
    const int dg = b * 256 + t;
    if (dg < N) {
        offo[dg] = base + exc;
        deg16[dg] = (unsigned short)v;
    }
    h[t] = 0;
    __syncthreads();
    const int tot = tot_sh;
    if (tot <= DCAP) {
        for (int i = t; i < cnt; i += 256) {
            unsigned int u = centries[s0 + i];
            int dl = u & 255;
            int r = atomicAdd(&h[dl], 1);
            stg[ex[dl] + r] = (unsigned short)(u >> 8);
        }
        __syncthreads();
        for (int i = v; i < pdv; ++i) stg[exc + i] = (unsigned short)N;  // pad
        __syncthreads();
        for (int i = t * 8; i < tot; i += 2048)
            *(int4*)(csr16 + base + i) = *(const int4*)(stg + i);
    } else {  // fallback (kept for correctness on skewed data)
        for (int i = t; i < cnt; i += 256) {
            unsigned int u = centries[s0 + i];
            int dl = u & 255;
            int r = atomicAdd(&h[dl], 1);
            csr16[base + ex[dl] + r] = (unsigned short)(u >> 8);
        }
        for (int i = v; i < pdv; ++i) csr16[base + exc + i] = (unsigned short)N;
    }
}

// ---------------- gather-mean (bf16 table -> packed fp32 A-frags) ----------------
// Half-wave per node; lane = 4 channels (8 B loads). Padded u16 CSR: pure
// unmasked 16-deep batches; sentinel rows are zero (L1-resident).
__global__ __launch_bounds__(256) void gather_mean_kernel(
    const unsigned short* __restrict__ featbf,
    const int* __restrict__ off,
    const unsigned short* __restrict__ deg16,
    const unsigned short* __restrict__ csr16,
    float* __restrict__ aggp)
{
    const int hw = (blockIdx.x * 256 + threadIdx.x) >> 5;   // node id (exact grid)
    const int l5 = threadIdx.x & 31;
    const unsigned short* fb = featbf + (size_t)l5 * 4;
    const int start = off[hw];
    const int dg = deg16[hw];
    const int pend = start + ((dg + 15) & ~15);
    f32x4 acc = {0.f, 0.f, 0.f, 0.f};
    for (int e = start; e < pend; e += 16) {
        const int4 w0 = *(const int4*)(csr16 + e);       // 8 idx
        const int4 w1 = *(const int4*)(csr16 + e + 8);   // 8 idx
        int sx[16];
        sx[0]  = w0.x & 0xffff;  sx[1]  = (unsigned)w0.x >> 16;
        sx[2]  = w0.y & 0xffff;  sx[3]  = (unsigned)w0.y >> 16;
        sx[4]  = w0.z & 0xffff;  sx[5]  = (unsigned)w0.z >> 16;
        sx[6]  = w0.w & 0xffff;  sx[7]  = (unsigned)w0.w >> 16;
        sx[8]  = w1.x & 0xffff;  sx[9]  = (unsigned)w1.x >> 16;
        sx[10] = w1.y & 0xffff;  sx[11] = (unsigned)w1.y >> 16;
        sx[12] = w1.z & 0xffff;  sx[13] = (unsigned)w1.z >> 16;
        sx[14] = w1.w & 0xffff;  sx[15] = (unsigned)w1.w >> 16;
        uint2 r[16];
#pragma unroll
        for (int p = 0; p < 16; ++p) r[p] = *(const uint2*)(fb + (size_t)sx[p] * D);
#pragma unroll
        for (int p = 0; p < 16; ++p) {
            acc.x += __uint_as_float(r[p].x << 16);
            acc.y += __uint_as_float(r[p].x & 0xffff0000u);
            acc.z += __uint_as_float(r[p].y << 16);
            acc.w += __uint_as_float(r[p].y & 0xffff0000u);
        }
    }
    float dinv = 1.0f / (float)max(dg, 1);
    acc *= dinv;
    const int tile = hw >> 4, r16 = hw & 15;
    const int ks = l5 >> 3, q = (l5 & 7) >> 1, jb = (l5 & 1) * 4;
    const size_t p = ((size_t)(tile * 4 + ks) * 64 + q * 16 + r16) * 8 + jb;
    *(f32x4*)(aggp + p) = acc;
}

// ---------------- dense MFMA GEMM, t-split: wave = (16-node tile) x (4 of 8 col-tiles) ----
__global__ __launch_bounds__(256) void sage_gemm_kernel(
    const float* __restrict__ aggp,             // packed A (k<128)
    const float* __restrict__ selfp,            // packed A (k>=128)
    const unsigned short* __restrict__ w_hi,
    const unsigned short* __restrict__ w_lo,
    const float* __restrict__ bias,
    float* __restrict__ opk,                    // nullable, packed fp32 (next self)
    unsigned short* __restrict__ outbf,         // nullable, row-major bf16
    int ntiles, int do_relu)
{
    const int wv = threadIdx.x >> 6;
    const int lane = threadIdx.x & 63;
    const int tile = blockIdx.x * 2 + (wv >> 1);
    const int th = (wv & 1) * 4;                // this wave's t-range: th..th+3
    if (tile >= ntiles) return;
    const int q = lane >> 4, r16 = lane & 15;
    const int n0w = tile * 16;

    f32x4 acc4[4];
#pragma unroll
    for (int t = 0; t < 4; ++t) acc4[t] = (f32x4){0.f, 0.f, 0.f, 0.f};

    const float* ap = aggp + (size_t)tile * 2048 + lane * 8;
    const float* sp = selfp + (size_t)tile * 2048 + lane * 8;

    for (int ks = 0; ks < 8; ++ks) {
        f32x4 a0, a1;
        if (ks < 4) {
            a0 = *(const f32x4*)(ap + ks * 512);
            a1 = *(const f32x4*)(ap + ks * 512 + 4);
        } else {
            a0 = *(const f32x4*)(sp + (ks - 4) * 512);
            a1 = *(const f32x4*)(sp + (ks - 4) * 512 + 4);
        }
        short8 BH[4], BL[4];
        const unsigned short* bh = w_hi + (size_t)(th * 8 + ks) * 512 + lane * 8;
        const unsigned short* bl = w_lo + (size_t)(th * 8 + ks) * 512 + lane * 8;
#pragma unroll
        for (int t = 0; t < 4; ++t) {
            BH[t] = *(const short8*)(bh + (size_t)t * 4096);
            BL[t] = *(const short8*)(bl + (size_t)t * 4096);
        }
        short8 ahi, alo;
#pragma unroll
        for (int i = 0; i < 8; ++i) {
            float vv = (i < 4) ? a0[i] : a1[i - 4];
            unsigned int h = f2bf_bits(vv);
            float hf = __uint_as_float(h << 16);
            unsigned int l = f2bf_bits(vv - hf);
            ahi[i] = (short)h;
            alo[i] = (short)l;
        }
#pragma unroll
        for (int t = 0; t < 4; ++t) {
            acc4[t] = __builtin_amdgcn_mfma_f32_16x16x32_bf16(ahi, BH[t], acc4[t], 0, 0, 0);
            acc4[t] = __builtin_amdgcn_mfma_f32_16x16x32_bf16(alo, BH[t], acc4[t], 0, 0, 0);
            acc4[t] = __builtin_amdgcn_mfma_f32_16x16x32_bf16(ahi, BL[t], acc4[t], 0, 0, 0);
        }
    }

    // epilogue: C/D layout col=lane&15, row=quad*4+reg
#pragma unroll
    for (int tt = 0; tt < 4; ++tt) {
        const int t = th + tt;
        const float bv = bias[t * 16 + r16];
#pragma unroll
        for (int r = 0; r < 4; ++r) {
            float vv = acc4[tt][r] + bv;
            if (do_relu) vv = fmaxf(vv, 0.f);
            if (opk) {
                const size_t p = ((size_t)(tile * 4 + (t >> 1)) * 64
                                  + ((t & 1) * 2 + (r16 >> 3)) * 16 + q * 4 + r) * 8
                                 + (r16 & 7);
                opk[p] = vv;
            }
            if (outbf) {
                outbf[(size_t)(n0w + q * 4 + r) * D + t * 16 + r16] =
                    (unsigned short)f2bf_bits(vv);
            }
        }
    }
}

// ---------------- edge dot-product decode (bf16 z rows) ----------------
__global__ __launch_bounds__(256) void pred_kernel(const unsigned short* __restrict__ zbf,
                                                   const int* __restrict__ ps,
                                                   const int* __restrict__ pd,
                                                   float* __restrict__ out, int EP) {
    int idx = blockIdx.x * blockDim.x + threadIdx.x;
    int e = idx >> 5;
    if (e >= EP) return;
    int l = idx & 31;
    const unsigned short* fb = zbf + (size_t)l * 4;
    uint2 ra = *(const uint2*)(fb + (size_t)ps[e] * D);
    uint2 rb = *(const uint2*)(fb + (size_t)pd[e] * D);
    float p = __uint_as_float(ra.x << 16)         * __uint_as_float(rb.x << 16)
            + __uint_as_float(ra.x & 0xffff0000u) * __uint_as_float(rb.x & 0xffff0000u)
            + __uint_as_float(ra.y << 16)         * __uint_as_float(rb.y << 16)
            + __uint_as_float(ra.y & 0xffff0000u) * __uint_as_float(rb.y & 0xffff0000u);
#pragma unroll
    for (int off = 16; off > 0; off >>= 1) p += __shfl_xor(p, off, 32);
    if (l == 0) out[e] = p;
}

extern "C" void kernel_launch(void* const* d_in, const int* in_sizes, int n_in,
                              void* d_out, int out_size, void* d_ws, size_t ws_size,
                              hipStream_t stream) {
    const float* x   = (const float*)d_in[0];
    const float* W1l = (const float*)d_in[1];
    const float* b1  = (const float*)d_in[2];
    const float* W1r = (const float*)d_in[3];
    const float* W2l = (const float*)d_in[4];
    const float* b2  = (const float*)d_in[5];
    const float* W2r = (const float*)d_in[6];
    const int* edge_index = (const int*)d_in[7];
    const int* pred_edges = (const int*)d_in[8];
    float* out = (float*)d_out;

    const int N  = in_sizes[0] / D;   // 50000
    const int E  = in_sizes[7] / 2;   // 800000
    const int EP = in_sizes[8] / 2;   // 200000

    const int* src = edge_index;
    const int* dst = edge_index + E;
    const int* ps  = pred_edges;
    const int* pd  = pred_edges + EP;

    // workspace layout (int-granular; csr16 region 16-B aligned by construction)
    int* part    = (int*)d_ws;                 // 64*256 = 16384
    int* cbase   = part + 16384;               // 272
    int* gcur    = cbase + 272;                // 256
    int* off     = gcur + 256;                 // 50016
    unsigned int* centries = (unsigned int*)(off + 50016);     // E
    unsigned short* csr16  = (unsigned short*)(centries + E);  // 1.6M u16 (800k ints)
    unsigned short* deg16  = csr16 + 1600000;                  // 50016 u16
    float* aggp  = (float*)(deg16 + 50032);    // N*D fp32 (packed mean)
    float* xpk   = aggp + (size_t)N * D;       // N*D fp32 (packed x)
    float* hpk   = xpk + (size_t)N * D;        // N*D fp32 (packed h)
    unsigned short* fbf   = (unsigned short*)(hpk + (size_t)N * D);  // (N+1)*D bf16
    unsigned short* w1_hi = fbf + (size_t)(N + 1) * D;               // 32768 each
    unsigned short* w1_lo = w1_hi + 32768;
    unsigned short* w2_hi = w1_lo + 32768;
    unsigned short* w2_lo = w2_hi + 32768;

    const int nblk_gather = N * 32 / 256;          // 6250 (exact)
    const int ntiles = N / 16;                     // 3125 (exact)
    const int nblk_gemm = (ntiles + 1) / 2;        // 1563
    const int nbC = (E + CCHUNK - 1) / CCHUNK;     // 196
    const int nbD = (N + 255) / 256;               // 196

    // fused prep: x pack | weight pack | coarse hist | zero row N
    prep_kernel<<<6571, 256, 0, stream>>>(x, W1l, W1r, W2l, W2r, dst,
                                          fbf, xpk,
                                          w1_hi, w1_lo, w2_hi, w2_lo,
                                          part, N, E);
    scan256_kernel<<<1, 256, 0, stream>>>(part, cbase, gcur);
    coarse_scatter_kernel<<<nbC, 256, 0, stream>>>(src, dst, gcur, centries, E);
    fine_bucket_kernel<<<nbD, 256, 0, stream>>>(centries, cbase, off, deg16, csr16, N, E);

    // layer 1: h = relu(mean(x)@W1l + x@W1r + b1) -> hpk (packed fp32) + fbf (bf16 h)
    gather_mean_kernel<<<nblk_gather, 256, 0, stream>>>(fbf, off, deg16, csr16, aggp);
    sage_gemm_kernel<<<nblk_gemm, 256, 0, stream>>>(aggp, xpk, w1_hi, w1_lo, b1,
                                                    hpk, fbf, ntiles, 1);
    // layer 2: z = mean(h)@W2l + h@W2r + b2 -> fbf (bf16 z)
    gather_mean_kernel<<<nblk_gather, 256, 0, stream>>>(fbf, off, deg16, csr16, aggp);
    sage_gemm_kernel<<<nblk_gemm, 256, 0, stream>>>(aggp, hpk, w2_hi, w2_lo, b2,
                                                    (float*)nullptr, fbf, ntiles, 0);
    // decode from bf16 z
    pred_kernel<<<(EP * 32 + 255) / 256, 256, 0, stream>>>(fbf, ps, pd, out, EP);
}

// Round 12
// 264.918 us; speedup vs baseline: 1.0680x; 1.0680x over previous
//
#include <hip/hip_runtime.h>

#define D 128

typedef __attribute__((ext_vector_type(8))) short short8;
typedef __attribute__((ext_vector_type(4))) float f32x4;

// fp32 -> bf16 bits, round-to-nearest-even
__device__ inline unsigned int f2bf_bits(float f) {
    unsigned int u = __float_as_uint(f);
    return (u + 0x7FFFu + ((u >> 16) & 1u)) >> 16;
}

// ---------------- fused prep: x cast+pack | weight pack | coarse hist | pad zero ----
// block roles: [0,6250) x-pack, [6250,6506) wsplit, [6506,6570) coarse hist
// (64 blocks, per-block partials -> no pre-zero), 6570 pad-zero.
__global__ __launch_bounds__(256) void prep_kernel(
    const float* __restrict__ x,
    const float* __restrict__ W1l, const float* __restrict__ W1r,
    const float* __restrict__ W2l, const float* __restrict__ W2r,
    const int* __restrict__ dst,
    unsigned short* __restrict__ fbf,
    float* __restrict__ xpk,
    unsigned short* __restrict__ w1_hi, unsigned short* __restrict__ w1_lo,
    unsigned short* __restrict__ w2_hi, unsigned short* __restrict__ w2_lo,
    int* __restrict__ part, int* __restrict__ csrpad, int E)
{
    const int t = threadIdx.x;
    const int b = blockIdx.x;
    if (b < 6250) {
        // x: row-major bf16 (gather) + packed A-frag fp32 (gemm self term)
        const int i = b * 256 + t;                 // 0..1599999
        const int hw = i >> 5, l5 = i & 31;
        f32x4 v = *(const f32x4*)(x + (size_t)hw * D + l5 * 4);
        ushort4 hv;
        hv.x = (unsigned short)f2bf_bits(v.x);
        hv.y = (unsigned short)f2bf_bits(v.y);
        hv.z = (unsigned short)f2bf_bits(v.z);
        hv.w = (unsigned short)f2bf_bits(v.w);
        *(ushort4*)(fbf + (size_t)hw * D + l5 * 4) = hv;
        const int tile = hw >> 4, r16 = hw & 15;
        const int ks = l5 >> 3, q = (l5 & 7) >> 1, jb = (l5 & 1) * 4;
        const size_t p = ((size_t)(tile * 4 + ks) * 64 + q * 16 + r16) * 8 + jb;
        *(f32x4*)(xpk + p) = v;
    } else if (b < 6506) {
        // weight pack: B-frag order + bf16 hi/lo split, both layers
        int gidx = (b - 6250) * 256 + t;           // 0..65535
        int sel = gidx >> 15;
        int idx = gidx & 32767;
        int tt = idx >> 12;
        int ks = (idx >> 9) & 7;
        int lane = (idx >> 3) & 63;
        int j = idx & 7;
        int q = lane >> 4, r16 = lane & 15;
        int k = ks * 32 + q * 8 + j;
        int c = tt * 16 + r16;
        const float* Wl = sel ? W2l : W1l;
        const float* Wr = sel ? W2r : W1r;
        float v = (k < 128) ? Wl[k * 128 + c] : Wr[(k - 128) * 128 + c];
        unsigned int h = f2bf_bits(v);
        float hf = __uint_as_float(h << 16);
        unsigned int l = f2bf_bits(v - hf);
        (sel ? w2_hi : w1_hi)[idx] = (unsigned short)h;
        (sel ? w2_lo : w1_lo)[idx] = (unsigned short)l;
    } else if (b < 6570) {
        __shared__ int h[256];
        h[t] = 0;
        __syncthreads();
        const int b3 = b - 6506;
        for (int e = b3 * 256 + t; e < E; e += 64 * 256)
            atomicAdd(&h[dst[e] >> 8], 1);
        __syncthreads();
        part[b3 * 256 + t] = h[t];
    } else {
        if (t < 16) csrpad[t] = 0;
    }
}

// ---------------- scan 256 bucket counts (sum of 64 per-block partials) ----------------
__global__ __launch_bounds__(256) void scan256_kernel(const int* __restrict__ part,
                                                      int* __restrict__ cbase,
                                                      int* __restrict__ gcur) {
    __shared__ int wsum[4];
    const int t = threadIdx.x, lane = t & 63, wv = t >> 6;
    int v = 0;
    for (int b = 0; b < 64; ++b) v += part[b * 256 + t];
    int s = v;
#pragma unroll
    for (int o = 1; o < 64; o <<= 1) {
        int u = __shfl_up(s, o, 64);
        if (lane >= o) s += u;
    }
    if (lane == 63) wsum[wv] = s;
    __syncthreads();
    int add = 0;
    for (int w = 0; w < wv; ++w) add += wsum[w];
    cbase[t + 1] = s + add;
    if (t == 0) cbase[0] = 0;
    gcur[t] = s + add - v;
}

// ---------------- coarse multisplit scatter ----------------
// Entry = (b<<24) | (src<<8) | (dst&255)   [src < 65536, b < 256]
#define CCHUNK 4096
__global__ __launch_bounds__(256) void coarse_scatter_kernel(
    const int* __restrict__ src, const int* __restrict__ dst,
    int* __restrict__ gcur, unsigned int* __restrict__ centries, int E)
{
    __shared__ int h[256];
    __shared__ int base[256];
    __shared__ unsigned int stage[CCHUNK];
    const int t = threadIdx.x;
    const int e0 = blockIdx.x * CCHUNK;
    h[t] = 0;
    __syncthreads();
#pragma unroll
    for (int i = 0; i < 16; ++i) {
        int e = e0 + i * 256 + t;
        unsigned int u = 0xFFFFFFFFu;
        if (e < E) {
            int d = dst[e];
            int s = src[e];
            int b = d >> 8;
            u = ((unsigned)b << 24) | ((unsigned)s << 8) | (unsigned)(d & 255);
            atomicAdd(&h[b], 1);
        }
        stage[i * 256 + t] = u;
    }
    __syncthreads();
    base[t] = atomicAdd(&gcur[t], h[t]);
    __syncthreads();
    h[t] = 0;
    __syncthreads();
#pragma unroll
    for (int i = 0; i < 16; ++i) {
        unsigned int u = stage[i * 256 + t];
        if (u != 0xFFFFFFFFu) {
            int b = u >> 24;
            int r = atomicAdd(&h[b], 1);
            int pos = base[b] + r;
            if (pos < E) centries[pos] = u & 0x00FFFFFFu;  // clamp guards rocprof replays
        }
    }
}

// ---------------- fine bucket: build off[] + CSR, LDS-staged ----------------
#define DCAP 8192
__global__ __launch_bounds__(256) void fine_bucket_kernel(
    const unsigned int* __restrict__ centries,
    const int* __restrict__ cbase,
    int* __restrict__ offo, int* __restrict__ csr, int N, int E)
{
    __shared__ int h[256], ex[256], wsum[4];
    __shared__ int stg[DCAP];
    const int t = threadIdx.x, lane = t & 63, wv = t >> 6;
    const int b = blockIdx.x;
    const int s0 = cbase[b];
    const int cnt = cbase[b + 1] - s0;
    h[t] = 0;
    __syncthreads();
    for (int i = t; i < cnt; i += 256)
        atomicAdd(&h[centries[s0 + i] & 255], 1);
    __syncthreads();
    int v = h[t], s = v;
#pragma unroll
    for (int o = 1; o < 64; o <<= 1) {
        int u = __shfl_up(s, o, 64);
        if (lane >= o) s += u;
    }
    if (lane == 63) wsum[wv] = s;
    __syncthreads();
    int add = 0;
    for (int w = 0; w < wv; ++w) add += wsum[w];
    const int exc = s + add - v;
    ex[t] = exc;
    const int dg = b * 256 + t;
    if (dg < N) offo[dg] = s0 + exc;
    if (b == 0 && t == 0) offo[N] = E;
    h[t] = 0;
    __syncthreads();
    if (cnt <= DCAP) {
        for (int i = t; i < cnt; i += 256) {
            unsigned int u = centries[s0 + i];
            int dl = u & 255;
            int r = atomicAdd(&h[dl], 1);
            stg[ex[dl] + r] = (int)(u >> 8);
        }
        __syncthreads();
        for (int i = t; i < cnt; i += 256)
            csr[s0 + i] = stg[i];
    } else {  // fallback (kept for correctness on skewed data)
        for (int i = t; i < cnt; i += 256) {
            unsigned int u = centries[s0 + i];
            int dl = u & 255;
            int r = atomicAdd(&h[dl], 1);
            csr[s0 + ex[dl] + r] = (int)(u >> 8);
        }
    }
}

// ---------------- gather-mean (bf16 table -> packed fp32 A-frags) ----------------
// Half-wave per node; lane = 4 channels (8 B loads). 16 rows always in flight;
// masked lanes clamp to the batch's first src (L1-resident line).
__global__ __launch_bounds__(256) void gather_mean_kernel(
    const unsigned short* __restrict__ featbf,
    const int* __restrict__ off,
    const int* __restrict__ csr,
    float* __restrict__ aggp)
{
    const int hw = (blockIdx.x * 256 + threadIdx.x) >> 5;   // node id (exact grid)
    const int l5 = threadIdx.x & 31;
    const unsigned short* fb = featbf + (size_t)l5 * 4;
    const int start = off[hw];
    const int end = off[hw + 1];
    f32x4 acc = {0.f, 0.f, 0.f, 0.f};
    for (int e = start; e < end; e += 16) {
        int4 ia = *(const int4*)(csr + e);
        int4 ib = *(const int4*)(csr + e + 4);
        int4 ic = *(const int4*)(csr + e + 8);
        int4 id = *(const int4*)(csr + e + 12);
        int sx[16];
        sx[0] = ia.x;  sx[1] = ia.y;  sx[2] = ia.z;  sx[3] = ia.w;
        sx[4] = ib.x;  sx[5] = ib.y;  sx[6] = ib.z;  sx[7] = ib.w;
        sx[8] = ic.x;  sx[9] = ic.y;  sx[10] = ic.z; sx[11] = ic.w;
        sx[12] = id.x; sx[13] = id.y; sx[14] = id.z; sx[15] = id.w;
#pragma unroll
        for (int p = 1; p < 16; ++p) sx[p] = (e + p < end) ? sx[p] : ia.x;
        uint2 r[16];
#pragma unroll
        for (int p = 0; p < 16; ++p) r[p] = *(const uint2*)(fb + (size_t)sx[p] * D);
#pragma unroll
        for (int p = 0; p < 16; ++p) {
            uint2 rv = r[p];
            if (e + p >= end) { rv.x = 0u; rv.y = 0u; }
            acc.x += __uint_as_float(rv.x << 16);
            acc.y += __uint_as_float(rv.x & 0xffff0000u);
            acc.z += __uint_as_float(rv.y << 16);
            acc.w += __uint_as_float(rv.y & 0xffff0000u);
        }
    }
    float dinv = 1.0f / (float)max(end - start, 1);
    acc *= dinv;
    const int tile = hw >> 4, r16 = hw & 15;
    const int ks = l5 >> 3, q = (l5 & 7) >> 1, jb = (l5 & 1) * 4;
    const size_t p = ((size_t)(tile * 4 + ks) * 64 + q * 16 + r16) * 8 + jb;
    *(f32x4*)(aggp + p) = acc;
}

// ---------------- dense MFMA GEMM, t-split: wave = (16-node tile) x (4 of 8 col-tiles) ----
// 1563 blocks x 4 waves = 24 waves/CU. fp32 packed A + in-kernel bf16x3
// convert; B halved per wave -> all 8 B-frag loads batchable in registers.
__global__ __launch_bounds__(256) void sage_gemm_kernel(
    const float* __restrict__ aggp,             // packed A (k<128)
    const float* __restrict__ selfp,            // packed A (k>=128)
    const unsigned short* __restrict__ w_hi,
    const unsigned short* __restrict__ w_lo,
    const float* __restrict__ bias,
    float* __restrict__ opk,                    // nullable, packed fp32 (next self)
    unsigned short* __restrict__ outbf,         // nullable, row-major bf16
    int ntiles, int do_relu)
{
    const int wv = threadIdx.x >> 6;
    const int lane = threadIdx.x & 63;
    const int tile = blockIdx.x * 2 + (wv >> 1);
    const int th = (wv & 1) * 4;                // this wave's t-range: th..th+3
    if (tile >= ntiles) return;
    const int q = lane >> 4, r16 = lane & 15;
    const int n0w = tile * 16;

    f32x4 acc4[4];
#pragma unroll
    for (int t = 0; t < 4; ++t) acc4[t] = (f32x4){0.f, 0.f, 0.f, 0.f};

    const float* ap = aggp + (size_t)tile * 2048 + lane * 8;
    const float* sp = selfp + (size_t)tile * 2048 + lane * 8;

    for (int ks = 0; ks < 8; ++ks) {
        f32x4 a0, a1;
        if (ks < 4) {
            a0 = *(const f32x4*)(ap + ks * 512);
            a1 = *(const f32x4*)(ap + ks * 512 + 4);
        } else {
            a0 = *(const f32x4*)(sp + (ks - 4) * 512);
            a1 = *(const f32x4*)(sp + (ks - 4) * 512 + 4);
        }
        short8 BH[4], BL[4];
        const unsigned short* bh = w_hi + (size_t)(th * 8 + ks) * 512 + lane * 8;
        const unsigned short* bl = w_lo + (size_t)(th * 8 + ks) * 512 + lane * 8;
#pragma unroll
        for (int t = 0; t < 4; ++t) {
            BH[t] = *(const short8*)(bh + (size_t)t * 4096);
            BL[t] = *(const short8*)(bl + (size_t)t * 4096);
        }
        short8 ahi, alo;
#pragma unroll
        for (int i = 0; i < 8; ++i) {
            float vv = (i < 4) ? a0[i] : a1[i - 4];
            unsigned int h = f2bf_bits(vv);
            float hf = __uint_as_float(h << 16);
            unsigned int l = f2bf_bits(vv - hf);
            ahi[i] = (short)h;
            alo[i] = (short)l;
        }
#pragma unroll
        for (int t = 0; t < 4; ++t) {
            acc4[t] = __builtin_amdgcn_mfma_f32_16x16x32_bf16(ahi, BH[t], acc4[t], 0, 0, 0);
            acc4[t] = __builtin_amdgcn_mfma_f32_16x16x32_bf16(alo, BH[t], acc4[t], 0, 0, 0);
            acc4[t] = __builtin_amdgcn_mfma_f32_16x16x32_bf16(ahi, BL[t], acc4[t], 0, 0, 0);
        }
    }

    // epilogue: C/D layout col=lane&15, row=quad*4+reg
#pragma unroll
    for (int tt = 0; tt < 4; ++tt) {
        const int t = th + tt;
        const float bv = bias[t * 16 + r16];
#pragma unroll
        for (int r = 0; r < 4; ++r) {
            float vv = acc4[tt][r] + bv;
            if (do_relu) vv = fmaxf(vv, 0.f);
            if (opk) {
                const size_t p = ((size_t)(tile * 4 + (t >> 1)) * 64
                                  + ((t & 1) * 2 + (r16 >> 3)) * 16 + q * 4 + r) * 8
                                 + (r16 & 7);
                opk[p] = vv;
            }
            if (outbf) {
                outbf[(size_t)(n0w + q * 4 + r) * D + t * 16 + r16] =
                    (unsigned short)f2bf_bits(vv);
            }
        }
    }
}

// ---------------- edge dot-product decode (bf16 z rows) ----------------
__global__ __launch_bounds__(256) void pred_kernel(const unsigned short* __restrict__ zbf,
                                                   const int* __restrict__ ps,
                                                   const int* __restrict__ pd,
                                                   float* __restrict__ out, int EP) {
    int idx = blockIdx.x * blockDim.x + threadIdx.x;
    int e = idx >> 5;
    if (e >= EP) return;
    int l = idx & 31;
    const unsigned short* fb = zbf + (size_t)l * 4;
    uint2 ra = *(const uint2*)(fb + (size_t)ps[e] * D);
    uint2 rb = *(const uint2*)(fb + (size_t)pd[e] * D);
    float p = __uint_as_float(ra.x << 16)         * __uint_as_float(rb.x << 16)
            + __uint_as_float(ra.x & 0xffff0000u) * __uint_as_float(rb.x & 0xffff0000u)
            + __uint_as_float(ra.y << 16)         * __uint_as_float(rb.y << 16)
            + __uint_as_float(ra.y & 0xffff0000u) * __uint_as_float(rb.y & 0xffff0000u);
#pragma unroll
    for (int off = 16; off > 0; off >>= 1) p += __shfl_xor(p, off, 32);
    if (l == 0) out[e] = p;
}

extern "C" void kernel_launch(void* const* d_in, const int* in_sizes, int n_in,
                              void* d_out, int out_size, void* d_ws, size_t ws_size,
                              hipStream_t stream) {
    const float* x   = (const float*)d_in[0];
    const float* W1l = (const float*)d_in[1];
    const float* b1  = (const float*)d_in[2];
    const float* W1r = (const float*)d_in[3];
    const float* W2l = (const float*)d_in[4];
    const float* b2  = (const float*)d_in[5];
    const float* W2r = (const float*)d_in[6];
    const int* edge_index = (const int*)d_in[7];
    const int* pred_edges = (const int*)d_in[8];
    float* out = (float*)d_out;

    const int N  = in_sizes[0] / D;   // 50000
    const int E  = in_sizes[7] / 2;   // 800000
    const int EP = in_sizes[8] / 2;   // 200000

    const int* src = edge_index;
    const int* dst = edge_index + E;
    const int* ps  = pred_edges;
    const int* pd  = pred_edges + EP;

    // workspace layout
    int* part    = (int*)d_ws;                 // 64*256
    int* cbase   = part + 16384;               // 257 (pad 272)
    int* gcur    = cbase + 272;                // 256
    int* off     = gcur + 256;                 // N+1 (pad 50016)
    unsigned int* centries = (unsigned int*)(off + 50016);  // E
    int* csr     = (int*)(centries + E);       // E + 16 pad
    float* aggp  = (float*)(csr + E + 16);     // N*D fp32 (packed mean)
    float* xpk   = aggp + (size_t)N * D;       // N*D fp32 (packed x)
    float* hpk   = xpk + (size_t)N * D;        // N*D fp32 (packed h)
    unsigned short* fbf   = (unsigned short*)(hpk + (size_t)N * D);  // N*D bf16
    unsigned short* w1_hi = fbf + (size_t)N * D;                     // 32768 each
    unsigned short* w1_lo = w1_hi + 32768;
    unsigned short* w2_hi = w1_lo + 32768;
    unsigned short* w2_lo = w2_hi + 32768;

    const int nblk_gather = N * 32 / 256;          // 6250 (exact)
    const int ntiles = N / 16;                     // 3125 (exact)
    const int nblk_gemm = (ntiles + 1) / 2;        // 1563
    const int nbC = (E + CCHUNK - 1) / CCHUNK;     // 196
    const int nbD = (N + 255) / 256;               // 196

    // fused prep: x pack | weight pack | coarse hist (64 blocks) | csr pad zero
    prep_kernel<<<6571, 256, 0, stream>>>(x, W1l, W1r, W2l, W2r, dst,
                                          fbf, xpk,
                                          w1_hi, w1_lo, w2_hi, w2_lo,
                                          part, csr + E, E);
    scan256_kernel<<<1, 256, 0, stream>>>(part, cbase, gcur);
    coarse_scatter_kernel<<<nbC, 256, 0, stream>>>(src, dst, gcur, centries, E);
    fine_bucket_kernel<<<nbD, 256, 0, stream>>>(centries, cbase, off, csr, N, E);

    // layer 1: h = relu(mean(x)@W1l + x@W1r + b1) -> hpk (packed fp32) + fbf (bf16 h)
    gather_mean_kernel<<<nblk_gather, 256, 0, stream>>>(fbf, off, csr, aggp);
    sage_gemm_kernel<<<nblk_gemm, 256, 0, stream>>>(aggp, xpk, w1_hi, w1_lo, b1,
                                                    hpk, fbf, ntiles, 1);
    // layer 2: z = mean(h)@W2l + h@W2r + b2 -> fbf (bf16 z)
    gather_mean_kernel<<<nblk_gather, 256, 0, stream>>>(fbf, off, csr, aggp);
    sage_gemm_kernel<<<nblk_gemm, 256, 0, stream>>>(aggp, hpk, w2_hi, w2_lo, b2,
                                                    (float*)nullptr, fbf, ntiles, 0);
    // decode from bf16 z
    pred_kernel<<<(EP * 32 + 255) / 256, 256, 0, stream>>>(fbf, ps, pd, out, EP);
}